// Round 8
// baseline (552.181 us; speedup 1.0000x reference)
//
#include <hip/hip_runtime.h>
#include <hip/hip_bf16.h>
#include <cstdint>
#include <cstddef>

#define B_ 128
#define D_ 1024
#define GEN_V_ 50000
#define OUT_V_ 50257
#define S_ 512

#define NTILE 128
#define NBLK 391         // ceil(GEN_V/128)
#define BK 64
#define NSTEP (D_ / BK)  // 16
#define CAP 8            // bucket capacity for inverted index (Poisson lambda~1)

typedef __attribute__((ext_vector_type(8))) short bf16x8;
typedef __attribute__((ext_vector_type(8))) unsigned short u16x8;
typedef __attribute__((ext_vector_type(4))) float f32x4;

__device__ __forceinline__ unsigned short f2bf(float f) {
  unsigned u = __float_as_uint(f);
  u += 0x7fffu + ((u >> 16) & 1u);   // RNE
  return (unsigned short)(u >> 16);
}

__device__ __forceinline__ bf16x8 pack8(float4 lo, float4 hi) {
  u16x8 h;
  h[0] = f2bf(lo.x); h[1] = f2bf(lo.y); h[2] = f2bf(lo.z); h[3] = f2bf(lo.w);
  h[4] = f2bf(hi.x); h[5] = f2bf(hi.y); h[6] = f2bf(hi.z); h[7] = f2bf(hi.w);
  return (bf16x8)h;
}

// ---------------- GEMM + fused exp + row partial sums -----------------------------
// elog[b][v] = exp(x@W_gen + b_gen);  rowpart[row][blk] = sum over this block's cols.
// BARRIER-FREE DIRECT-LOAD: M=128 means W has ZERO reuse within a block, so LDS
// staging of W is pure layout-shuffle overhead (R3-R7: ~85% idle in the
// stage/drain/barrier chain regardless of prefetch depth). Instead each lane loads
// its MFMA fragments straight from global:
//   B: per-lane loop-invariant 32-bit offsets offs[j]=(koff0+j)*GEN_V+n (8 regs/nt),
//      wave-uniform base Wk advanced per step in SALU; ks=32 via second uniform base.
//      Zero per-load address VALU. Each 64B line consumed exactly once by one quad.
//   A: x is 0.5MB, L2-resident; per-lane float4 pairs with immediate offsets.
// No LDS (except 512B srow), no __syncthreads in the K-loop, pure dataflow vmcnt.
// Block: 512 threads (8 waves, 2(M)x4(N)), tile M=128 x N=128, wave 64x32, acc[4][2].
__global__ __launch_bounds__(512, 4) void gemm_kernel(
    const float* __restrict__ x, const float* __restrict__ W,
    const float* __restrict__ bgen, float* __restrict__ elog,
    float* __restrict__ rowpart) {
  __shared__ float srow[B_];
  int tid = threadIdx.x;
  int lane = tid & 63;
  int wv = tid >> 6;            // 0..7
  int wm = wv & 1;              // m half (64)
  int wn = wv >> 1;             // n quarter (32 cols)
  int nbase = blockIdx.x * NTILE;
  int l15 = lane & 15;
  int quad = lane >> 4;
  int koff0 = quad * 8;

  f32x4 acc[4][2];
#pragma unroll
  for (int i = 0; i < 4; i++)
#pragma unroll
    for (int j = 0; j < 2; j++) acc[i][j] = (f32x4){0.f, 0.f, 0.f, 0.f};

  // B: per-lane element offsets (clamped to stay in-bounds; epilogue masks invalid)
  int n0 = nbase + wn * 32 + l15;
  int n1 = n0 + 16;
  unsigned n0c = (unsigned)((n0 < GEN_V_) ? n0 : (GEN_V_ - 1));
  unsigned n1c = (unsigned)((n1 < GEN_V_) ? n1 : (GEN_V_ - 1));
  unsigned offs0[8], offs1[8];
#pragma unroll
  for (int j = 0; j < 8; j++) {
    offs0[j] = (unsigned)((koff0 + j) * GEN_V_) + n0c;
    offs1[j] = (unsigned)((koff0 + j) * GEN_V_) + n1c;
  }
  // A: per-lane row pointers (4 m-tiles), k-origin koff0
  const float* xp0 = x + (size_t)(wm * 64 + 0 * 16 + l15) * D_ + koff0;
  const float* xp1 = x + (size_t)(wm * 64 + 1 * 16 + l15) * D_ + koff0;
  const float* xp2 = x + (size_t)(wm * 64 + 2 * 16 + l15) * D_ + koff0;
  const float* xp3 = x + (size_t)(wm * 64 + 3 * 16 + l15) * D_ + koff0;

  const float* Wk = W;   // wave-uniform; advances BK*GEN_V per step (SALU)
  for (int t = 0; t < NSTEP; ++t) {
    int k0 = t * BK;
#pragma unroll
    for (int ks = 0; ks < 2; ks++) {          // half-steps: k-local 0 / 32
      const float* Wh = Wk + (size_t)(ks * 32) * GEN_V_;   // uniform
      int ka = k0 + ks * 32;
      // ---- issue loads: B 16 dwords (offset-form), A 8 float4 (imm-form) ----
      float b0[8], b1[8];
#pragma unroll
      for (int j = 0; j < 8; j++) { b0[j] = Wh[offs0[j]]; b1[j] = Wh[offs1[j]]; }
      float4 a0l = *(const float4*)(xp0 + ka), a0h = *(const float4*)(xp0 + ka + 4);
      float4 a1l = *(const float4*)(xp1 + ka), a1h = *(const float4*)(xp1 + ka + 4);
      float4 a2l = *(const float4*)(xp2 + ka), a2h = *(const float4*)(xp2 + ka + 4);
      float4 a3l = *(const float4*)(xp3 + ka), a3h = *(const float4*)(xp3 + ka + 4);
      // ---- convert to bf16 fragments ----
      u16x8 hb0, hb1;
#pragma unroll
      for (int j = 0; j < 8; j++) { hb0[j] = f2bf(b0[j]); hb1[j] = f2bf(b1[j]); }
      bf16x8 bfr0 = (bf16x8)hb0, bfr1 = (bf16x8)hb1;
      bf16x8 af0 = pack8(a0l, a0h);
      bf16x8 af1 = pack8(a1l, a1h);
      bf16x8 af2 = pack8(a2l, a2h);
      bf16x8 af3 = pack8(a3l, a3h);
      // ---- 8 MFMAs ----
      acc[0][0] = __builtin_amdgcn_mfma_f32_16x16x32_bf16(af0, bfr0, acc[0][0], 0, 0, 0);
      acc[0][1] = __builtin_amdgcn_mfma_f32_16x16x32_bf16(af0, bfr1, acc[0][1], 0, 0, 0);
      acc[1][0] = __builtin_amdgcn_mfma_f32_16x16x32_bf16(af1, bfr0, acc[1][0], 0, 0, 0);
      acc[1][1] = __builtin_amdgcn_mfma_f32_16x16x32_bf16(af1, bfr1, acc[1][1], 0, 0, 0);
      acc[2][0] = __builtin_amdgcn_mfma_f32_16x16x32_bf16(af2, bfr0, acc[2][0], 0, 0, 0);
      acc[2][1] = __builtin_amdgcn_mfma_f32_16x16x32_bf16(af2, bfr1, acc[2][1], 0, 0, 0);
      acc[3][0] = __builtin_amdgcn_mfma_f32_16x16x32_bf16(af3, bfr0, acc[3][0], 0, 0, 0);
      acc[3][1] = __builtin_amdgcn_mfma_f32_16x16x32_bf16(af3, bfr1, acc[3][1], 0, 0, 0);
    }
    Wk += (size_t)BK * GEN_V_;
  }

  // ---- epilogue: e = exp(acc + bias); store elog; per-row partial sums ----
  if (tid < B_) srow[tid] = 0.f;
  __syncthreads();
  int rquad = quad * 4;
#pragma unroll
  for (int nt = 0; nt < 2; nt++) {
    int cg = nbase + wn * 32 + nt * 16 + l15;
    bool cv = cg < GEN_V_;
    float bgv = cv ? bgen[cg] : 0.f;
#pragma unroll
    for (int mt = 0; mt < 4; mt++) {
      int rb = wm * 64 + mt * 16 + rquad;
#pragma unroll
      for (int r = 0; r < 4; r++) {
        float e = __expf(acc[mt][nt][r] + bgv);   // logits in ±~5: no max-sub needed
        float contrib = cv ? e : 0.f;
        if (cv) elog[(size_t)(rb + r) * GEN_V_ + cg] = e;
        // reduce across the 16 lanes sharing this row (stays within quad)
#pragma unroll
        for (int o = 1; o < 16; o <<= 1) contrib += __shfl_xor(contrib, o);
        if (l15 == 0) atomicAdd(&srow[rb + r], contrib);
      }
    }
  }
  __syncthreads();
  if (tid < B_) rowpart[(size_t)tid * NBLK + blockIdx.x] = srow[tid];
}

// ------------- inverted index of g2o: fixed-cap buckets + overflow list -------------
__global__ void build_index_kernel(const int* __restrict__ g2o, int* __restrict__ cnt,
                                   int* __restrict__ vlist, int* __restrict__ novf,
                                   int* __restrict__ ovf) {
  int v = blockIdx.x * 256 + threadIdx.x;
  if (v < GEN_V_) {
    int o = g2o[v];
    int slot = atomicAdd(&cnt[o], 1);
    if (slot < CAP) {
      vlist[o * CAP + slot] = v;
    } else {
      int i = atomicAdd(novf, 1);
      ovf[2 * i] = o;
      ovf[2 * i + 1] = v;
    }
  }
}

// ------------- rowsum + gate fused: rowscale[b] = sigmoid(x·Wg+bg) / sum_b ---------
__global__ void rowsum_gate_kernel(const float* __restrict__ rowpart,
                                   const float* __restrict__ x, const float* __restrict__ Wg,
                                   const float* __restrict__ bg,
                                   float* __restrict__ interp, float* __restrict__ rowscale) {
  int b = blockIdx.x, t = threadIdx.x;  // 128 blocks x 256
  const float* rp = rowpart + (size_t)b * NBLK;
  float s = 0.f;
  for (int i = t; i < NBLK; i += 256) s += rp[i];
  // gate dot-product: D/4 = 256 float4 chunks, exactly one per thread
  const float4* xr = (const float4*)(x + (size_t)b * D_);
  const float4* wr = (const float4*)Wg;
  float4 xv = xr[t], wv = wr[t];
  float g = xv.x * wv.x + xv.y * wv.y + xv.z * wv.z + xv.w * wv.w;
  for (int o = 32; o > 0; o >>= 1) {
    s += __shfl_down(s, o);
    g += __shfl_down(g, o);
  }
  __shared__ float reds[4], redg[4];
  int lane = t & 63, w = t >> 6;
  if (lane == 0) { reds[w] = s; redg[w] = g; }
  __syncthreads();
  if (t == 0) {
    float tot = redg[0] + redg[1] + redg[2] + redg[3] + bg[0];
    float itp = 1.f / (1.f + __expf(-tot));
    float sum = reds[0] + reds[1] + reds[2] + reds[3];
    interp[b] = itp;
    rowscale[b] = itp / sum;
  }
}

// -------- gen gather: out[b,o] = rowscale_b * sum_{v in bucket(o)} elog[b,v] --------
// XCD b-affinity: block id -> b = (id&7)*16 + ((id>>3)&15), oc = id>>7.
#define GATHER_NB (128 * 197)   // 197 = ceil(OUT_V/256) o-chunks x 128 b
__global__ void gather_gen_kernel(const float* __restrict__ elog, const int* __restrict__ cnt,
                                  const int* __restrict__ vlist,
                                  const float* __restrict__ rowscale, float* __restrict__ out) {
  int id = blockIdx.x;
  int b = (id & 7) * 16 + ((id >> 3) & 15);
  int o = (id >> 7) * 256 + threadIdx.x;
  if (o < OUT_V_) {
    int c = cnt[o];
    if (c > CAP) c = CAP;
    const float* lrow = elog + (size_t)b * GEN_V_;
    const int* vl = vlist + (size_t)o * CAP;
    float s = 0.f;
    for (int j = 0; j < c; j++) s += lrow[vl[j]];
    out[(size_t)b * OUT_V_ + o] = s * rowscale[b];
  }
}

// ---------------- overflow cleanup (normally novf==0): atomic adds ------------------
__global__ void ovf_kernel(const int* __restrict__ novf, const int* __restrict__ ovf,
                           const float* __restrict__ elog, const float* __restrict__ rowscale,
                           float* __restrict__ out) {
  int n = novf[0];
  if (n == 0) return;
  int total = n * B_;
  for (int i = blockIdx.x * 256 + threadIdx.x; i < total; i += gridDim.x * 256) {
    int e = i >> 7;          // entry
    int b = i & 127;         // row
    int o = ovf[2 * e];
    int v = ovf[2 * e + 1];
    atomicAdd(&out[(size_t)b * OUT_V_ + o], rowscale[b] * elog[(size_t)b * GEN_V_ + v]);
  }
}

// ---------------- ptr scatter: out[b, i2o[ctx[b,s]]] += (1-interp_b) * alphas[b,s] --
__global__ void scatter_ptr_kernel(const float* __restrict__ alphas, const int* __restrict__ ctx,
                                   const int* __restrict__ i2o, const float* __restrict__ interp,
                                   float* __restrict__ out) {
  int b = blockIdx.x, s = threadIdx.x;  // 512 threads
  float w = 1.f - interp[b];
  int o = i2o[ctx[b * S_ + s]];
  atomicAdd(&out[(size_t)b * OUT_V_ + o], w * alphas[b * S_ + s]);
}

extern "C" void kernel_launch(void* const* d_in, const int* in_sizes, int n_in,
                              void* d_out, int out_size, void* d_ws, size_t ws_size,
                              hipStream_t stream) {
  const float* x      = (const float*)d_in[0];
  const float* alphas = (const float*)d_in[1];
  const float* Wg     = (const float*)d_in[2];
  const float* bg     = (const float*)d_in[3];
  const float* Wgen   = (const float*)d_in[4];
  const float* bgen   = (const float*)d_in[5];
  const int*   ctx    = (const int*)d_in[6];
  const int*   g2o    = (const int*)d_in[7];
  const int*   i2o    = (const int*)d_in[8];
  float* out = (float*)d_out;

  // workspace layout (4B elems):
  // elog[128*50000] | interp[128] | rowscale[128] | rowpart[128*NBLK]
  // | cnt[OUT_V] | novf[1] | vlist[OUT_V*CAP] | ovf[2*GEN_V]
  float* elog      = (float*)d_ws;
  float* interp    = elog + (size_t)B_ * GEN_V_;
  float* rowscale  = interp + B_;
  float* rowpart   = rowscale + B_;
  int*   cnt       = (int*)(rowpart + (size_t)B_ * NBLK);
  int*   novf      = cnt + OUT_V_;
  int*   vlist     = novf + 1;
  int*   ovf       = vlist + (size_t)OUT_V_ * CAP;

  // zero cnt + novf in one contiguous memset
  hipMemsetAsync(cnt, 0, (OUT_V_ + 1) * sizeof(int), stream);

  build_index_kernel<<<(GEN_V_ + 255) / 256, 256, 0, stream>>>(g2o, cnt, vlist, novf, ovf);
  gemm_kernel<<<NBLK, 512, 0, stream>>>(x, Wgen, bgen, elog, rowpart);
  rowsum_gate_kernel<<<B_, 256, 0, stream>>>(rowpart, x, Wg, bg, interp, rowscale);
  gather_gen_kernel<<<GATHER_NB, 256, 0, stream>>>(elog, cnt, vlist, rowscale, out);
  ovf_kernel<<<64, 256, 0, stream>>>(novf, ovf, elog, rowscale, out);
  scatter_ptr_kernel<<<B_, S_, 0, stream>>>(alphas, ctx, i2o, interp, out);
}